// Round 3
// baseline (232.571 us; speedup 1.0000x reference)
//
#include <hip/hip_runtime.h>
#include <hip/hip_fp16.h>
#include <stdint.h>

// x[16384,2048] f32, w[2048,2048] f32, bias[2048] f32, scalar scales.
// M=16384, N=2048, K=2048. Output f16 values stored as f32.
#define MDIM 16384
#define NDIM 2048
#define KDIM 2048

typedef __attribute__((ext_vector_type(4))) float f32x4;

// ---------------------------------------------------------------------------
// Bit-exact f32 -> e4m3fn (OCP) RTNE after clip to +-448.
// ---------------------------------------------------------------------------
__device__ __forceinline__ unsigned f32_to_e4m3(float x) {
    float q = fminf(448.f, fmaxf(-448.f, x));
    unsigned ub = __float_as_uint(q);
    unsigned sgn = (ub >> 24) & 0x80u;
    float aq = fabsf(q);
    int E = (int)((__float_as_uint(aq) >> 23) & 0xff) - 127;
    if (E < -6) E = -6;
    float quantum = __uint_as_float((unsigned)(E + 124) << 23);
    int m = (int)rintf(aq / quantum);
    if (m == 16) { m = 8; E += 1; }
    unsigned bits;
    if (m < 8) bits = sgn | (unsigned)m;
    else       bits = sgn | ((unsigned)(E + 7) << 3) | (unsigned)(m - 8);
    return bits;
}

__global__ void quant_fp8_kernel(const float* __restrict__ x,
                                 uint8_t* __restrict__ q,
                                 const float* __restrict__ scale,
                                 unsigned n16) {
    float sc = scale[0];
    unsigned i = blockIdx.x * blockDim.x + threadIdx.x;
    unsigned stride = gridDim.x * blockDim.x;
    for (; i < n16; i += stride) {
        const float4* xp = (const float4*)(x + (size_t)i * 16);
        uint32_t w[4];
#pragma unroll
        for (int j = 0; j < 4; ++j) {
            float4 v = xp[j];
            unsigned b0 = f32_to_e4m3(v.x / sc);
            unsigned b1 = f32_to_e4m3(v.y / sc);
            unsigned b2 = f32_to_e4m3(v.z / sc);
            unsigned b3 = f32_to_e4m3(v.w / sc);
            w[j] = b0 | (b1 << 8) | (b2 << 16) | (b3 << 24);
        }
        ((uint4*)q)[i] = make_uint4(w[0], w[1], w[2], w[3]);
    }
}

// ---------------------------------------------------------------------------
// GEMM: C[M][N] = Aq[M][K] * Bq[N][K]^T, fp8 e4m3, mfma_f32_16x16x32_fp8_fp8.
// 256x256 tile, BK=64 bytes, 8 waves (2Mx4N), per-wave out 128x64.
// 4 phases per K-tile (mh 0/1 x kk 0/1), 16 MFMA per phase.
// Pipelined staging: 1 gload_lds unit per phase, counted vmcnt(1) per K-tile
// (never drained in the main loop), raw fenced s_barrier.
//
// LDS (64 KiB static, dbuf 32 KiB each): per buf, A 16 KiB + B 16 KiB.
// Chunk swizzle P(row,c) = row*4 + ((c+row)&3): linear gload_lds dest, the
// inverse permutation applied to the per-lane GLOBAL source, same perm on
// the fragment reads (proven in round 2: bank-floor pattern).
//
// Units (1 load/thread each, 8 KiB): A-unit u = rows [u*64,u*64+64) U
// [128+u*64, 128+u*64+64)  (the mh=u rows of both wave-rows: dead after the
// mh=u phases). B-unit u = rows [u*128, u*128+128) (read every phase).
// Steady schedule within tile t (phases p0..p3):
//   p0: issue A1(t+1)   (A1(t-1) dead at end of t-1)
//   p1: issue B0(t+1)   (B0(t-1) dead at end of t-1)
//   p2: issue B1(t+1)
//   p3: issue A0(t+2)   (A0(t) dead after p1) ; then vmcnt(1); barrier
// Entry wait leaves only A0(t+1) in flight -> everything tile t needs landed.
// ---------------------------------------------------------------------------
#define BM 256
#define BN 256
#define BKB 64
#define NT (KDIM / BKB)   // 32

__device__ __forceinline__ void gload_lds16(const uint8_t* g, uint8_t* l) {
    __builtin_amdgcn_global_load_lds(
        (const __attribute__((address_space(1))) void*)g,
        (__attribute__((address_space(3))) void*)l, 16, 0, 0);
}

__device__ __forceinline__ void barrier_fenced() {
    asm volatile("" ::: "memory");
    __builtin_amdgcn_s_barrier();
    asm volatile("" ::: "memory");
}

__global__ __launch_bounds__(512, 2) void gemm_fp8_kernel(
    const uint8_t* __restrict__ Aq, const uint8_t* __restrict__ Bq,
    const float* __restrict__ bias, const float* __restrict__ s_in,
    const float* __restrict__ s_w, float* __restrict__ out) {

    __shared__ uint8_t lds[65536];

    // XCD-aware bijective swizzle (nwg = 512, divisible by 8)
    int nwg = gridDim.x;
    int cpx = nwg >> 3;
    int bid = blockIdx.x;
    int swz = (bid & 7) * cpx + (bid >> 3);
    int tm = swz >> 3;                 // tiles_n = 8
    int tn = swz & 7;
    int row0 = tm * BM;
    int col0 = tn * BN;

    int tid  = threadIdx.x;
    int lane = tid & 63;
    int wid  = tid >> 6;
    int wr = wid >> 2, wc = wid & 3;
    int wrBase = wr * 128, wcBase = wc * 64;
    int r15 = lane & 15;
    int g   = lane >> 4;
    int ghalf = g >> 1;
    int h8  = (g & 1) << 3;

    // staging coords (1 x 16B chunk per thread per unit)
    int rsub = tid >> 2;                          // 0..127
    int c_l  = ((tid & 3) - rsub) & 3;            // inverse chunk perm
    int arow = (rsub & 63) + ((rsub >> 6) << 7);  // A row interleave (+u*64)
    int pc16 = (tid & 3) << 4;                    // phys chunk byte offset

    const uint8_t* Asrc = Aq + (size_t)row0 * KDIM;
    const uint8_t* Bsrc = Bq + (size_t)col0 * KDIM;

    // stage A-unit u of K-tile kt
#define STAGE_A(U, KT)                                                        \
    gload_lds16(Asrc + (size_t)(arow + (U) * 64) * KDIM + (KT) * BKB + c_l * 16, \
                &lds[(((KT) & 1) << 15) + (arow + (U) * 64) * 64 + pc16])
    // stage B-unit u of K-tile kt
#define STAGE_B(U, KT)                                                        \
    gload_lds16(Bsrc + (size_t)((U) * 128 + rsub) * KDIM + (KT) * BKB + c_l * 16, \
                &lds[(((KT) & 1) << 15) + 16384 + ((U) * 128 + rsub) * 64 + pc16])

    f32x4 acc[8][4];
#pragma unroll
    for (int m = 0; m < 8; ++m)
#pragma unroll
        for (int n = 0; n < 4; ++n)
            acc[m][n] = (f32x4){0.f, 0.f, 0.f, 0.f};

    // ---- prologue: A0(0), A1(0), B0(0), B1(0), A0(1); wait all but last ----
    STAGE_A(0, 0); STAGE_A(1, 0); STAGE_B(0, 0); STAGE_B(1, 0);
    STAGE_A(0, 1);
    asm volatile("s_waitcnt vmcnt(1)" ::: "memory");
    barrier_fenced();

    // one compute phase: 8 ds_read_b64 + 16 MFMA
#define PHASE(MH, KK)                                                         \
    {                                                                         \
        const uint8_t* Ab = &lds[bo];                                         \
        const uint8_t* Bb = &lds[bo + 16384];                                 \
        int po = ((((KK) << 1) + ghalf + r15) & 3) * 16 + h8;                 \
        long af[4], bf[4];                                                    \
        _Pragma("unroll")                                                     \
        for (int m_ = 0; m_ < 4; ++m_)                                        \
            af[m_] = *(const long*)(Ab +                                      \
                (wrBase + (MH) * 64 + m_ * 16 + r15) * 64 + po);              \
        _Pragma("unroll")                                                     \
        for (int n_ = 0; n_ < 4; ++n_)                                        \
            bf[n_] = *(const long*)(Bb +                                      \
                (wcBase + n_ * 16 + r15) * 64 + po);                          \
        __builtin_amdgcn_s_setprio(1);                                        \
        _Pragma("unroll")                                                     \
        for (int m_ = 0; m_ < 4; ++m_)                                        \
            _Pragma("unroll")                                                 \
            for (int n_ = 0; n_ < 4; ++n_)                                    \
                acc[(MH) * 4 + m_][n_] =                                      \
                    __builtin_amdgcn_mfma_f32_16x16x32_fp8_fp8(               \
                        af[m_], bf[n_], acc[(MH) * 4 + m_][n_], 0, 0, 0);     \
        __builtin_amdgcn_s_setprio(0);                                        \
    }

    for (int t = 0; t < NT; ++t) {
        const unsigned bo = (unsigned)(t & 1) << 15;
        // p0: compute (mh0,kk0); issue A1(t+1)
        if (t + 1 < NT) STAGE_A(1, t + 1);
        PHASE(0, 0);
        barrier_fenced();
        // p1: (mh0,kk1); issue B0(t+1)
        if (t + 1 < NT) STAGE_B(0, t + 1);
        PHASE(0, 1);
        barrier_fenced();
        // p2: (mh1,kk0); issue B1(t+1)
        if (t + 1 < NT) STAGE_B(1, t + 1);
        PHASE(1, 0);
        barrier_fenced();
        // p3: (mh1,kk1); issue A0(t+2); counted wait for tile t+1's data
        if (t + 2 < NT) STAGE_A(0, t + 2);
        PHASE(1, 1);
        if (t + 2 < NT) asm volatile("s_waitcnt vmcnt(1)" ::: "memory");
        else            asm volatile("s_waitcnt vmcnt(0)" ::: "memory");
        barrier_fenced();
    }

    // ---- epilogue: fp16 double-rounding emulation, store f32 ----
    float s = s_in[0] * s_w[0];
    int g4 = g * 4;
#pragma unroll
    for (int n = 0; n < 4; ++n) {
        int col = col0 + wcBase + n * 16 + r15;
        __half hb = __float2half(bias[col]);
#pragma unroll
        for (int m = 0; m < 8; ++m) {
            int rbase = row0 + wrBase + m * 16 + g4;
#pragma unroll
            for (int r = 0; r < 4; ++r) {
                __half h = __float2half(acc[m][n][r] * s);
                out[(size_t)(rbase + r) * NDIM + col] = __half2float(__hadd(h, hb));
            }
        }
    }
#undef PHASE
#undef STAGE_A
#undef STAGE_B
}

// ---------------------------------------------------------------------------
extern "C" void kernel_launch(void* const* d_in, const int* in_sizes, int n_in,
                              void* d_out, int out_size, void* d_ws, size_t ws_size,
                              hipStream_t stream) {
    const float* x      = (const float*)d_in[0];   // [16384, 2048]
    const float* weight = (const float*)d_in[1];   // [2048, 2048]
    const float* bias   = (const float*)d_in[2];   // [2048]
    const float* s_in   = (const float*)d_in[3];   // [1]
    const float* s_w    = (const float*)d_in[4];   // [1]
    float* out          = (float*)d_out;

    uint8_t* xq = (uint8_t*)d_ws;                          // 33.5 MB
    uint8_t* wq = (uint8_t*)d_ws + (size_t)MDIM * KDIM;    // 4.2 MB

    quant_fp8_kernel<<<2048, 256, 0, stream>>>(x, xq, s_in,
        (unsigned)((size_t)MDIM * KDIM / 16));
    quant_fp8_kernel<<<512, 256, 0, stream>>>(weight, wq, s_w,
        (unsigned)((size_t)NDIM * KDIM / 16));

    dim3 grid((MDIM / BM) * (NDIM / BN));   // 64 * 8 = 512
    gemm_fp8_kernel<<<grid, 512, 0, stream>>>(xq, wq, bias, s_in, s_w, out);
}

// Round 4
// 137.445 us; speedup vs baseline: 1.6921x; 1.6921x over previous
//
#include <hip/hip_runtime.h>
#include <hip/hip_fp16.h>
#include <stdint.h>

// x[16384,2048] f32, w[2048,2048] f32, bias[2048] f32, scalar scales.
// M=16384, N=2048, K=2048. Output f16 values stored as f32.
#define MDIM 16384
#define NDIM 2048
#define KDIM 2048

typedef __attribute__((ext_vector_type(4))) float f32x4;
typedef __attribute__((ext_vector_type(4))) int   i32x4;
typedef __attribute__((ext_vector_type(8))) int   i32x8;

// ---------------------------------------------------------------------------
// Bit-exact f32 -> e4m3fn (OCP) RTNE after clip to +-448.
// ---------------------------------------------------------------------------
__device__ __forceinline__ unsigned f32_to_e4m3(float x) {
    float q = fminf(448.f, fmaxf(-448.f, x));
    unsigned ub = __float_as_uint(q);
    unsigned sgn = (ub >> 24) & 0x80u;
    float aq = fabsf(q);
    int E = (int)((__float_as_uint(aq) >> 23) & 0xff) - 127;
    if (E < -6) E = -6;
    float quantum = __uint_as_float((unsigned)(E + 124) << 23);
    int m = (int)rintf(aq / quantum);
    if (m == 16) { m = 8; E += 1; }
    unsigned bits;
    if (m < 8) bits = sgn | (unsigned)m;
    else       bits = sgn | ((unsigned)(E + 7) << 3) | (unsigned)(m - 8);
    return bits;
}

__global__ void quant_fp8_kernel(const float* __restrict__ x,
                                 uint8_t* __restrict__ q,
                                 const float* __restrict__ scale,
                                 unsigned n16) {
    float sc = scale[0];
    unsigned i = blockIdx.x * blockDim.x + threadIdx.x;
    unsigned stride = gridDim.x * blockDim.x;
    for (; i < n16; i += stride) {
        const float4* xp = (const float4*)(x + (size_t)i * 16);
        uint32_t w[4];
#pragma unroll
        for (int j = 0; j < 4; ++j) {
            float4 v = xp[j];
            unsigned b0 = f32_to_e4m3(v.x / sc);
            unsigned b1 = f32_to_e4m3(v.y / sc);
            unsigned b2 = f32_to_e4m3(v.z / sc);
            unsigned b3 = f32_to_e4m3(v.w / sc);
            w[j] = b0 | (b1 << 8) | (b2 << 16) | (b3 << 24);
        }
        ((uint4*)q)[i] = make_uint4(w[0], w[1], w[2], w[3]);
    }
}

// ---------------------------------------------------------------------------
// GEMM: C[M][N] = Aq[M][K] * Bq[N][K]^T, fp8 e4m3, via
// mfma_scale_f32_16x16x128_f8f6f4 with unit scales (e8m0 127 -> 2^0, exact;
// numerically identical to non-scaled fp8 MFMA, 2x the rate, and each lane's
// fragment is 32 CONTIGUOUS K-bytes -> ds_read_b128 pairs).
//
// 128x128 tile, BK=128 bytes, 16 K-tiles, 4 waves (2x2, 64x64 each),
// simple 2-barrier K-loop (round-3 pipelining disproven: LDS-bound).
//
// Chunk swizzle (8 chunks of 16B per row): P(row,c) = row*8 + ((c+row)&7).
// Staging: linear gload_lds dest at chunk p; global source uses inverse
// (row = p>>3, c = ((p&7)-row)&7). Fragment read: lane needs logical chunks
// (2g, 2g+1) of its row -> phys ((2g+row)&7), ((2g+1+row)&7). A quarter-wave
// (16 lanes, g fixed) covers all 8 16B bank-slots (2-way r15/r15+8 pairs) ->
// conflict-free b128 service vs round 3's 4-way b64 serialization.
// ---------------------------------------------------------------------------
#define BM 128
#define BN 128
#define BKB 128
#define NKT (KDIM / BKB)   // 16

__device__ __forceinline__ void gload_lds16(const uint8_t* g, uint8_t* l) {
    __builtin_amdgcn_global_load_lds(
        (const __attribute__((address_space(1))) void*)g,
        (__attribute__((address_space(3))) void*)l, 16, 0, 0);
}

__global__ __launch_bounds__(256) void gemm_fp8_kernel(
    const uint8_t* __restrict__ Aq, const uint8_t* __restrict__ Bq,
    const float* __restrict__ bias, const float* __restrict__ s_in,
    const float* __restrict__ s_w, float* __restrict__ out) {

    __shared__ uint8_t lsA[BM * BKB];   // 16 KiB
    __shared__ uint8_t lsB[BN * BKB];   // 16 KiB

    // XCD-aware bijective swizzle (nwg = 2048, divisible by 8)
    int nwg = gridDim.x;
    int cpx = nwg >> 3;
    int bid = blockIdx.x;
    int swz = (bid & 7) * cpx + (bid >> 3);
    int tiles_n = NDIM / BN;            // 16
    int tm = swz / tiles_n;
    int tn = swz % tiles_n;
    int row0 = tm * BM;
    int col0 = tn * BN;

    int t = threadIdx.x;
    int lane = t & 63;
    int wid = t >> 6;
    int wr = wid >> 1;                  // 0..1
    int wc = wid & 1;                   // 0..1
    int wrBase = wr * 64, wcBase = wc * 64;
    int r15 = lane & 15;
    int g   = lane >> 4;                // 0..3 -> k-block = g*32 bytes

    f32x4 acc[4][4];
#pragma unroll
    for (int m = 0; m < 4; ++m)
#pragma unroll
        for (int n = 0; n < 4; ++n)
            acc[m][n] = (f32x4){0.f, 0.f, 0.f, 0.f};

    // staging coords: 4 chunks per thread per tile (1024 chunks / 256 thr)
    int sp[4], srow[4], sc[4];
#pragma unroll
    for (int i = 0; i < 4; ++i) {
        int p = i * 256 + t;
        sp[i]   = p;
        srow[i] = p >> 3;
        sc[i]   = ((p & 7) - srow[i]) & 7;
    }

    const uint8_t* Abase = Aq + (size_t)row0 * KDIM;
    const uint8_t* Bbase = Bq + (size_t)col0 * KDIM;

    for (int kt = 0; kt < NKT; ++kt) {
        int koff = kt * BKB;
#pragma unroll
        for (int i = 0; i < 4; ++i)
            gload_lds16(Abase + (size_t)srow[i] * KDIM + koff + sc[i] * 16,
                        &lsA[sp[i] * 16]);
#pragma unroll
        for (int i = 0; i < 4; ++i)
            gload_lds16(Bbase + (size_t)srow[i] * KDIM + koff + sc[i] * 16,
                        &lsB[sp[i] * 16]);
        __syncthreads();

        i32x8 af[4], bf[4];
#pragma unroll
        for (int m = 0; m < 4; ++m) {
            int row = wrBase + m * 16 + r15;
            const uint8_t* rp = &lsA[row * BKB];
            i32x4 lo = *(const i32x4*)(rp + (((2 * g + row) & 7) << 4));
            i32x4 hi = *(const i32x4*)(rp + (((2 * g + 1 + row) & 7) << 4));
#pragma unroll
            for (int j = 0; j < 4; ++j) { af[m][j] = lo[j]; af[m][4 + j] = hi[j]; }
        }
#pragma unroll
        for (int n = 0; n < 4; ++n) {
            int row = wcBase + n * 16 + r15;
            const uint8_t* rp = &lsB[row * BKB];
            i32x4 lo = *(const i32x4*)(rp + (((2 * g + row) & 7) << 4));
            i32x4 hi = *(const i32x4*)(rp + (((2 * g + 1 + row) & 7) << 4));
#pragma unroll
            for (int j = 0; j < 4; ++j) { bf[n][j] = lo[j]; bf[n][4 + j] = hi[j]; }
        }

#pragma unroll
        for (int m = 0; m < 4; ++m)
#pragma unroll
            for (int n = 0; n < 4; ++n)
                acc[m][n] = __builtin_amdgcn_mfma_scale_f32_16x16x128_f8f6f4(
                    af[m], bf[n], acc[m][n],
                    0, 0,          // cbsz=fp8(e4m3), blgp=fp8(e4m3)
                    0, 127,        // opsel_a, scale_a byte0 = 127 -> 1.0
                    0, 127);       // opsel_b, scale_b
        __syncthreads();
    }

    // ---- epilogue: fp16 double-rounding emulation, store f32 ----
    float s = s_in[0] * s_w[0];
    int crow = row0 + wrBase;
    int ccol = col0 + wcBase;
#pragma unroll
    for (int n = 0; n < 4; ++n) {
        int col = ccol + n * 16 + r15;
        __half hb = __float2half(bias[col]);
#pragma unroll
        for (int m = 0; m < 4; ++m) {
            int rbase = crow + m * 16 + g * 4;
#pragma unroll
            for (int r = 0; r < 4; ++r) {
                __half h = __float2half(acc[m][n][r] * s);
                out[(size_t)(rbase + r) * NDIM + col] = __half2float(__hadd(h, hb));
            }
        }
    }
}

// ---------------------------------------------------------------------------
extern "C" void kernel_launch(void* const* d_in, const int* in_sizes, int n_in,
                              void* d_out, int out_size, void* d_ws, size_t ws_size,
                              hipStream_t stream) {
    const float* x      = (const float*)d_in[0];   // [16384, 2048]
    const float* weight = (const float*)d_in[1];   // [2048, 2048]
    const float* bias   = (const float*)d_in[2];   // [2048]
    const float* s_in   = (const float*)d_in[3];   // [1]
    const float* s_w    = (const float*)d_in[4];   // [1]
    float* out          = (float*)d_out;

    uint8_t* xq = (uint8_t*)d_ws;                          // 33.5 MB
    uint8_t* wq = (uint8_t*)d_ws + (size_t)MDIM * KDIM;    // 4.2 MB

    quant_fp8_kernel<<<2048, 256, 0, stream>>>(x, xq, s_in,
        (unsigned)((size_t)MDIM * KDIM / 16));
    quant_fp8_kernel<<<512, 256, 0, stream>>>(weight, wq, s_w,
        (unsigned)((size_t)NDIM * KDIM / 16));

    dim3 grid((MDIM / BM) * (NDIM / BN));   // 128 * 16 = 2048
    gemm_fp8_kernel<<<grid, 256, 0, stream>>>(xq, wq, bias, s_in, s_w, out);
}

// Round 5
// 129.690 us; speedup vs baseline: 1.7933x; 1.0598x over previous
//
#include <hip/hip_runtime.h>
#include <hip/hip_fp16.h>
#include <stdint.h>

// x[16384,2048] f32, w[2048,2048] f32, bias[2048] f32, scalar scales.
// M=16384, N=2048, K=2048. Output f16 values stored as f32.
#define MDIM 16384
#define NDIM 2048
#define KDIM 2048

typedef __attribute__((ext_vector_type(4))) float f32x4;
typedef __attribute__((ext_vector_type(4))) int   i32x4;
typedef __attribute__((ext_vector_type(8))) int   i32x8;

// ---------------------------------------------------------------------------
// Bit-exact f32 -> e4m3fn (OCP) RTNE after clip to +-448.
// ---------------------------------------------------------------------------
__device__ __forceinline__ unsigned f32_to_e4m3(float x) {
    float q = fminf(448.f, fmaxf(-448.f, x));
    unsigned ub = __float_as_uint(q);
    unsigned sgn = (ub >> 24) & 0x80u;
    float aq = fabsf(q);
    int E = (int)((__float_as_uint(aq) >> 23) & 0xff) - 127;
    if (E < -6) E = -6;
    float quantum = __uint_as_float((unsigned)(E + 124) << 23);
    int m = (int)rintf(aq / quantum);
    if (m == 16) { m = 8; E += 1; }
    unsigned bits;
    if (m < 8) bits = sgn | (unsigned)m;
    else       bits = sgn | ((unsigned)(E + 7) << 3) | (unsigned)(m - 8);
    return bits;
}

__global__ void quant_fp8_kernel(const float* __restrict__ x,
                                 uint8_t* __restrict__ q,
                                 const float* __restrict__ scale,
                                 unsigned n16) {
    float sc = scale[0];
    unsigned i = blockIdx.x * blockDim.x + threadIdx.x;
    unsigned stride = gridDim.x * blockDim.x;
    for (; i < n16; i += stride) {
        const float4* xp = (const float4*)(x + (size_t)i * 16);
        uint32_t w[4];
#pragma unroll
        for (int j = 0; j < 4; ++j) {
            float4 v = xp[j];
            unsigned b0 = f32_to_e4m3(v.x / sc);
            unsigned b1 = f32_to_e4m3(v.y / sc);
            unsigned b2 = f32_to_e4m3(v.z / sc);
            unsigned b3 = f32_to_e4m3(v.w / sc);
            w[j] = b0 | (b1 << 8) | (b2 << 16) | (b3 << 24);
        }
        ((uint4*)q)[i] = make_uint4(w[0], w[1], w[2], w[3]);
    }
}

// ---------------------------------------------------------------------------
// GEMM: C[M][N] = Aq[M][K] * Bq[N][K]^T, fp8 e4m3, via
// mfma_scale_f32_16x16x128_f8f6f4, unit scales (exact; 2x fp8 rate; 32
// contiguous K-bytes per lane fragment -> ds_read_b128, proven round 4).
//
// 256x256 tile, BK=128B, 16 K-tiles, 8 waves (2Mx4N), 128KiB LDS dbuf.
// Counted-vmcnt 2-phase schedule (T3+T4+T5):
//   units/tile: A0,A1 (M-halves, interleaved rows), B0,B1 (N-halves);
//   each unit = 2 gload_lds instr/thread (16KiB).
//   p0: issue A0(t+1),B0(t+1); read bf[4]+af[4](mh0); 16 MFMA; vmcnt(4); bar
//   p1: issue B1(t+1),A1(t+1); read af[4](mh1);       16 MFMA; vmcnt(2); bar
// Invariant entering tile t: only A1(t) (2 instr) outstanding; p0's vmcnt(4)
// lands it before p1's reads. Main loop never drains vmcnt to 0.
//
// Chunk swizzle per 128B row (8x16B): phys pc = ((c + r) & 7), linear
// gload_lds dest, inverse perm on global src, same perm on fragment reads
// (round-4 verified: 2-way residual only).
// ---------------------------------------------------------------------------
#define BM 256
#define BN 256
#define BKB 128
#define NKT (KDIM / BKB)   // 16

__device__ __forceinline__ void gload_lds16(const uint8_t* g, uint8_t* l) {
    __builtin_amdgcn_global_load_lds(
        (const __attribute__((address_space(1))) void*)g,
        (__attribute__((address_space(3))) void*)l, 16, 0, 0);
}

__device__ __forceinline__ void barrier_fenced() {
    asm volatile("" ::: "memory");
    __builtin_amdgcn_s_barrier();
    asm volatile("" ::: "memory");
}

__global__ __launch_bounds__(512) void gemm_fp8_kernel(
    const uint8_t* __restrict__ Aq, const uint8_t* __restrict__ Bq,
    const float* __restrict__ bias, const float* __restrict__ s_in,
    const float* __restrict__ s_w, float* __restrict__ out) {

    extern __shared__ uint8_t lds[];   // 131072 bytes (2 x 64KiB buffers)

    // XCD-aware bijective swizzle (nwg = 512, divisible by 8)
    int nwg = gridDim.x;
    int cpx = nwg >> 3;
    int bid = blockIdx.x;
    int swz = (bid & 7) * cpx + (bid >> 3);
    int tm = swz >> 3;                 // tiles_n = 8
    int tn = swz & 7;
    int row0 = tm * BM;
    int col0 = tn * BN;

    int tid  = threadIdx.x;
    int lane = tid & 63;
    int wid  = tid >> 6;
    int wr = wid >> 2, wc = wid & 3;   // 2M x 4N
    int r15 = lane & 15;
    int g   = lane >> 4;

    // fragment-read swizzle offsets (bytes within a row's 8 chunks)
    int perm0 = ((2 * g + r15) & 7) << 4;
    int perm1 = ((2 * g + 1 + r15) & 7) << 4;

    // ---- staging coordinates: unit = 1024 chunks (128 rows), 2 per thread --
    int pj[2]   = {tid, 512 + tid};
    int rj[2], cj[2];
#pragma unroll
    for (int j = 0; j < 2; ++j) {
        rj[j] = pj[j] >> 3;
        cj[j] = ((pj[j] & 7) - (rj[j] & 7)) & 7;
    }
    // A-unit local row -> global row: (r&63) + ((r>>6)<<7)  [+ U*64]
    size_t asrcoff[2], bsrcoff[2];
    int    adst[2], bdst[2];
#pragma unroll
    for (int j = 0; j < 2; ++j) {
        int ar = (rj[j] & 63) + ((rj[j] >> 6) << 7);
        asrcoff[j] = (size_t)ar * KDIM + cj[j] * 16;
        bsrcoff[j] = (size_t)rj[j] * KDIM + cj[j] * 16;
        adst[j] = pj[j] * 16;             // + U*16384
        bdst[j] = 32768 + pj[j] * 16;     // + U*16384
    }

    const uint8_t* Asrc = Aq + (size_t)row0 * KDIM;
    const uint8_t* Bsrc = Bq + (size_t)col0 * KDIM;
    uint8_t* stdst = &lds[0];             // staging dest buffer (tile kt & 1)

#define STAGE_A(U, KT)                                                        \
    {                                                                         \
        _Pragma("unroll")                                                     \
        for (int j_ = 0; j_ < 2; ++j_)                                        \
            gload_lds16(Asrc + asrcoff[j_] + (size_t)(U) * 64 * KDIM +        \
                            (size_t)(KT) * BKB,                               \
                        stdst + adst[j_] + (U) * 16384);                      \
    }
#define STAGE_B(U, KT)                                                        \
    {                                                                         \
        _Pragma("unroll")                                                     \
        for (int j_ = 0; j_ < 2; ++j_)                                        \
            gload_lds16(Bsrc + bsrcoff[j_] + (size_t)(U) * 128 * KDIM +       \
                            (size_t)(KT) * BKB,                               \
                        stdst + bdst[j_] + (U) * 16384);                      \
    }

    f32x4 acc[8][4];
#pragma unroll
    for (int m = 0; m < 8; ++m)
#pragma unroll
        for (int n = 0; n < 4; ++n)
            acc[m][n] = (f32x4){0.f, 0.f, 0.f, 0.f};

    // ---- prologue: all 4 units of tile 0; A1 youngest; leave A1 in flight --
    STAGE_A(0, 0); STAGE_B(0, 0); STAGE_B(1, 0); STAGE_A(1, 0);
    asm volatile("s_waitcnt vmcnt(2)" ::: "memory");
    barrier_fenced();

    // fragment LDS base offsets (element-invariant parts)
    int aRowBase = wr * 64;                        // + m*16 + r15
    int bUnit = (wc >> 1) * 1024;
    int bRowBase = (wc & 1) * 64;                  // + n*16 + r15

    i32x8 bf[4], af[4];

#define LOAD_BF(bo)                                                           \
    _Pragma("unroll")                                                         \
    for (int n_ = 0; n_ < 4; ++n_) {                                          \
        int rB = bRowBase + n_ * 16 + r15;                                    \
        const uint8_t* rp = lds + (bo) + 32768 + (bUnit + rB * 8) * 16;       \
        i32x4 lo = *(const i32x4*)(rp + perm0);                               \
        i32x4 hi = *(const i32x4*)(rp + perm1);                               \
        _Pragma("unroll")                                                     \
        for (int q_ = 0; q_ < 4; ++q_) { bf[n_][q_] = lo[q_]; bf[n_][4 + q_] = hi[q_]; } \
    }

#define LOAD_AF(bo, MH)                                                       \
    _Pragma("unroll")                                                         \
    for (int m_ = 0; m_ < 4; ++m_) {                                          \
        int rA = aRowBase + m_ * 16 + r15;                                    \
        const uint8_t* rp = lds + (bo) + ((MH) * 1024 + rA * 8) * 16;         \
        i32x4 lo = *(const i32x4*)(rp + perm0);                               \
        i32x4 hi = *(const i32x4*)(rp + perm1);                               \
        _Pragma("unroll")                                                     \
        for (int q_ = 0; q_ < 4; ++q_) { af[m_][q_] = lo[q_]; af[m_][4 + q_] = hi[q_]; } \
    }

#define MFMA_BLOCK(MH)                                                        \
    __builtin_amdgcn_s_setprio(1);                                            \
    _Pragma("unroll")                                                         \
    for (int m_ = 0; m_ < 4; ++m_)                                            \
        _Pragma("unroll")                                                     \
        for (int n_ = 0; n_ < 4; ++n_)                                        \
            acc[(MH) * 4 + m_][n_] =                                          \
                __builtin_amdgcn_mfma_scale_f32_16x16x128_f8f6f4(             \
                    af[m_], bf[n_], acc[(MH) * 4 + m_][n_],                   \
                    0, 0, 0, 127, 0, 127);                                    \
    __builtin_amdgcn_s_setprio(0);

    for (int t = 0; t < NKT; ++t) {
        const unsigned bo = (unsigned)(t & 1) << 16;
        stdst = &lds[(unsigned)((t + 1) & 1) << 16];
        if (t + 1 < NKT) {
            // ---- p0: prefetch A0,B0(t+1); compute mh0 ----
            STAGE_A(0, t + 1);
            STAGE_B(0, t + 1);
            LOAD_BF(bo);
            LOAD_AF(bo, 0);
            MFMA_BLOCK(0);
            asm volatile("s_waitcnt vmcnt(4)" ::: "memory");
            barrier_fenced();
            // ---- p1: prefetch B1,A1(t+1); compute mh1 ----
            STAGE_B(1, t + 1);
            STAGE_A(1, t + 1);
            LOAD_AF(bo, 1);
            MFMA_BLOCK(1);
            asm volatile("s_waitcnt vmcnt(2)" ::: "memory");
            barrier_fenced();
        } else {
            // ---- last tile: drain ----
            LOAD_BF(bo);
            LOAD_AF(bo, 0);
            MFMA_BLOCK(0);
            asm volatile("s_waitcnt vmcnt(0)" ::: "memory");
            barrier_fenced();
            LOAD_AF(bo, 1);
            MFMA_BLOCK(1);
        }
    }

    // ---- epilogue: fp16 double-rounding emulation, store f32 ----
    float s = s_in[0] * s_w[0];
    int g4 = g * 4;
#pragma unroll
    for (int n = 0; n < 4; ++n) {
        int col = col0 + wc * 64 + n * 16 + r15;
        __half hb = __float2half(bias[col]);
#pragma unroll
        for (int mh = 0; mh < 2; ++mh)
#pragma unroll
            for (int m = 0; m < 4; ++m) {
                int rbase = row0 + wr * 128 + mh * 64 + m * 16 + g4;
#pragma unroll
                for (int r = 0; r < 4; ++r) {
                    __half h = __float2half(acc[mh * 4 + m][n][r] * s);
                    out[(size_t)(rbase + r) * NDIM + col] =
                        __half2float(__hadd(h, hb));
                }
            }
    }
#undef STAGE_A
#undef STAGE_B
#undef LOAD_BF
#undef LOAD_AF
#undef MFMA_BLOCK
}

// ---------------------------------------------------------------------------
extern "C" void kernel_launch(void* const* d_in, const int* in_sizes, int n_in,
                              void* d_out, int out_size, void* d_ws, size_t ws_size,
                              hipStream_t stream) {
    const float* x      = (const float*)d_in[0];   // [16384, 2048]
    const float* weight = (const float*)d_in[1];   // [2048, 2048]
    const float* bias   = (const float*)d_in[2];   // [2048]
    const float* s_in   = (const float*)d_in[3];   // [1]
    const float* s_w    = (const float*)d_in[4];   // [1]
    float* out          = (float*)d_out;

    uint8_t* xq = (uint8_t*)d_ws;                          // 33.5 MB
    uint8_t* wq = (uint8_t*)d_ws + (size_t)MDIM * KDIM;    // 4.2 MB

    quant_fp8_kernel<<<2048, 256, 0, stream>>>(x, xq, s_in,
        (unsigned)((size_t)MDIM * KDIM / 16));
    quant_fp8_kernel<<<512, 256, 0, stream>>>(weight, wq, s_w,
        (unsigned)((size_t)NDIM * KDIM / 16));

    dim3 grid((MDIM / BM) * (NDIM / BN));   // 64 * 8 = 512
    gemm_fp8_kernel<<<grid, 512, 131072, stream>>>(xq, wq, bias, s_in, s_w, out);
}

// Round 6
// 119.639 us; speedup vs baseline: 1.9439x; 1.0840x over previous
//
#include <hip/hip_runtime.h>
#include <hip/hip_fp16.h>
#include <stdint.h>

// x[16384,2048] f32, w[2048,2048] f32, bias[2048] f32, scalar scales.
// M=16384, N=2048, K=2048. Output f16 values stored as f32.
#define MDIM 16384
#define NDIM 2048
#define KDIM 2048

typedef __attribute__((ext_vector_type(4))) float f32x4;
typedef __attribute__((ext_vector_type(4))) int   i32x4;
typedef __attribute__((ext_vector_type(8))) int   i32x8;

// ---------------------------------------------------------------------------
// Bit-exact f32 -> e4m3fn (OCP) RTNE after clip to +-448.
// aq/quantum replaced by aq * 2^(3-E)  (exact pow2 scale, saves the div seq).
// ---------------------------------------------------------------------------
__device__ __forceinline__ unsigned f32_to_e4m3(float x) {
    float q = fminf(448.f, fmaxf(-448.f, x));
    unsigned ub = __float_as_uint(q);
    unsigned sgn = (ub >> 24) & 0x80u;
    float aq = fabsf(q);
    int E = (int)((__float_as_uint(aq) >> 23) & 0xff) - 127;
    if (E < -6) E = -6;
    float rq = __uint_as_float((unsigned)(130 - E) << 23);  // 2^(3-E), exact
    int m = (int)rintf(aq * rq);                            // RTNE, exact scale
    if (m == 16) { m = 8; E += 1; }
    unsigned bits;
    if (m < 8) bits = sgn | (unsigned)m;
    else       bits = sgn | ((unsigned)(E + 7) << 3) | (unsigned)(m - 8);
    return bits;
}

__device__ __forceinline__ void quant_span(const float* __restrict__ x,
                                           uint8_t* __restrict__ q, float sc,
                                           unsigned i0, unsigned stride,
                                           unsigned n16) {
    for (unsigned i = i0; i < n16; i += stride) {
        const float4* xp = (const float4*)(x + (size_t)i * 16);
        uint32_t w[4];
#pragma unroll
        for (int j = 0; j < 4; ++j) {
            float4 v = xp[j];
            unsigned b0 = f32_to_e4m3(v.x / sc);
            unsigned b1 = f32_to_e4m3(v.y / sc);
            unsigned b2 = f32_to_e4m3(v.z / sc);
            unsigned b3 = f32_to_e4m3(v.w / sc);
            w[j] = b0 | (b1 << 8) | (b2 << 16) | (b3 << 24);
        }
        ((uint4*)q)[i] = make_uint4(w[0], w[1], w[2], w[3]);
    }
}

// Single dispatch: blocks [0,2048) quantize x, [2048,2304) quantize w.
__global__ void quant_both_kernel(const float* __restrict__ x,
                                  uint8_t* __restrict__ xq,
                                  const float* __restrict__ w,
                                  uint8_t* __restrict__ wq,
                                  const float* __restrict__ s_in,
                                  const float* __restrict__ s_w) {
    if (blockIdx.x < 2048) {
        unsigned i0 = blockIdx.x * blockDim.x + threadIdx.x;
        quant_span(x, xq, s_in[0], i0, 2048 * 256,
                   (unsigned)((size_t)MDIM * KDIM / 16));
    } else {
        unsigned i0 = (blockIdx.x - 2048) * blockDim.x + threadIdx.x;
        quant_span(w, wq, s_w[0], i0, 256 * 256,
                   (unsigned)((size_t)NDIM * KDIM / 16));
    }
}

// ---------------------------------------------------------------------------
// GEMM: C[M][N] = Aq[M][K] * Bq[N][K]^T, fp8 e4m3, via
// mfma_scale_f32_16x16x128_f8f6f4, unit scales (exact, 2x fp8 rate, 32
// contiguous K-bytes/lane -> ds_read_b128; proven rounds 4-5).
//
// 256x256 tile, BK=128B, 16 K-tiles, 8 waves (2Mx4N), 128KiB LDS dbuf.
// Deep-prefetch 2-phase schedule (round-5 postmortem: >=2-phase cover for
// every staged unit; ONE counted vmcnt per tile, mid-tile barrier is pure
// wave-sync):
//   invariant entering tile t: all 4 units of t landed; outstanding =
//     A0(t+1),B0(t+1) (4 instr).
//   p0: issue B1(t+1),A1(t+1) [-> buf (t+1)&1]; LOAD_BF+LOAD_AF(mh0);
//       16 MFMA; barrier.           (p0 consumes A0,B0,B1 regions of bo)
//   p1: issue A0(t+2),B0(t+2) [-> buf t&1 = bo; regions consumed in p0];
//       LOAD_AF(mh1); 16 MFMA; vmcnt(4); barrier.
// Cover: B1/A1(t+1) ~2 phases; A0/B0(t+1) ~3 phases (all > HBM latency).
//
// Chunk swizzle per 128B row (8x16B): phys pc = ((c + r) & 7); linear
// gload_lds dest, inverse perm on global src, same perm on fragment reads
// (2-way residual only, measured rounds 4-5).
// ---------------------------------------------------------------------------
#define BM 256
#define BN 256
#define BKB 128
#define NKT (KDIM / BKB)   // 16

__device__ __forceinline__ void gload_lds16(const uint8_t* g, uint8_t* l) {
    __builtin_amdgcn_global_load_lds(
        (const __attribute__((address_space(1))) void*)g,
        (__attribute__((address_space(3))) void*)l, 16, 0, 0);
}

__device__ __forceinline__ void barrier_fenced() {
    asm volatile("" ::: "memory");
    __builtin_amdgcn_s_barrier();
    asm volatile("" ::: "memory");
}

__global__ __launch_bounds__(512) void gemm_fp8_kernel(
    const uint8_t* __restrict__ Aq, const uint8_t* __restrict__ Bq,
    const float* __restrict__ bias, const float* __restrict__ s_in,
    const float* __restrict__ s_w, float* __restrict__ out) {

    extern __shared__ uint8_t lds[];   // 131072 bytes (2 x 64KiB buffers)

    // XCD-aware bijective swizzle (nwg = 512, divisible by 8).
    // The 8 blocks sharing an A-panel (same tm) land on the same XCD/L2.
    int nwg = gridDim.x;
    int cpx = nwg >> 3;
    int bid = blockIdx.x;
    int swz = (bid & 7) * cpx + (bid >> 3);
    int tm = swz >> 3;                 // tiles_n = 8
    int tn = swz & 7;
    int row0 = tm * BM;
    int col0 = tn * BN;

    int tid  = threadIdx.x;
    int lane = tid & 63;
    int wid  = tid >> 6;
    int wr = wid >> 2, wc = wid & 3;   // 2M x 4N
    int r15 = lane & 15;
    int g   = lane >> 4;

    // fragment-read swizzle offsets (bytes within a row's 8 chunks)
    int perm0 = ((2 * g + r15) & 7) << 4;
    int perm1 = ((2 * g + 1 + r15) & 7) << 4;

    // ---- staging coordinates: unit = 1024 chunks (128 rows), 2 per thread --
    int pj[2] = {tid, 512 + tid};
    int rj[2], cj[2];
#pragma unroll
    for (int j = 0; j < 2; ++j) {
        rj[j] = pj[j] >> 3;
        cj[j] = ((pj[j] & 7) - (rj[j] & 7)) & 7;
    }
    size_t asrcoff[2], bsrcoff[2];
    int    adst[2], bdst[2];
#pragma unroll
    for (int j = 0; j < 2; ++j) {
        int ar = (rj[j] & 63) + ((rj[j] >> 6) << 7);   // A row interleave
        asrcoff[j] = (size_t)ar * KDIM + cj[j] * 16;
        bsrcoff[j] = (size_t)rj[j] * KDIM + cj[j] * 16;
        adst[j] = pj[j] * 16;             // + U*16384
        bdst[j] = 32768 + pj[j] * 16;     // + U*16384
    }

    const uint8_t* Asrc = Aq + (size_t)row0 * KDIM;
    const uint8_t* Bsrc = Bq + (size_t)col0 * KDIM;

#define STAGE_A(U, KT, DST)                                                   \
    {                                                                         \
        _Pragma("unroll")                                                     \
        for (int j_ = 0; j_ < 2; ++j_)                                        \
            gload_lds16(Asrc + asrcoff[j_] + (size_t)(U) * 64 * KDIM +        \
                            (size_t)(KT) * BKB,                               \
                        (DST) + adst[j_] + (U) * 16384);                      \
    }
#define STAGE_B(U, KT, DST)                                                   \
    {                                                                         \
        _Pragma("unroll")                                                     \
        for (int j_ = 0; j_ < 2; ++j_)                                        \
            gload_lds16(Bsrc + bsrcoff[j_] + (size_t)(U) * 128 * KDIM +       \
                            (size_t)(KT) * BKB,                               \
                        (DST) + bdst[j_] + (U) * 16384);                      \
    }

    f32x4 acc[8][4];
#pragma unroll
    for (int m = 0; m < 8; ++m)
#pragma unroll
        for (int n = 0; n < 4; ++n)
            acc[m][n] = (f32x4){0.f, 0.f, 0.f, 0.f};

    // ---- prologue: all of tile 0, then A0(1),B0(1); leave those in flight --
    {
        uint8_t* b0 = &lds[0];
        uint8_t* b1 = &lds[65536];
        STAGE_A(0, 0, b0); STAGE_B(0, 0, b0); STAGE_B(1, 0, b0); STAGE_A(1, 0, b0);
        STAGE_A(0, 1, b1); STAGE_B(0, 1, b1);
        asm volatile("s_waitcnt vmcnt(4)" ::: "memory");
        barrier_fenced();
    }

    int aRowBase = wr * 64;                        // + m*16 + r15
    int bUnit = (wc >> 1) * 1024;
    int bRowBase = (wc & 1) * 64;                  // + n*16 + r15

    i32x8 bf[4], af[4];

#define LOAD_BF(bo)                                                           \
    _Pragma("unroll")                                                         \
    for (int n_ = 0; n_ < 4; ++n_) {                                          \
        int rB = bRowBase + n_ * 16 + r15;                                    \
        const uint8_t* rp = lds + (bo) + 32768 + (bUnit + rB * 8) * 16;       \
        i32x4 lo = *(const i32x4*)(rp + perm0);                               \
        i32x4 hi = *(const i32x4*)(rp + perm1);                               \
        _Pragma("unroll")                                                     \
        for (int q_ = 0; q_ < 4; ++q_) { bf[n_][q_] = lo[q_]; bf[n_][4 + q_] = hi[q_]; } \
    }

#define LOAD_AF(bo, MH)                                                       \
    _Pragma("unroll")                                                         \
    for (int m_ = 0; m_ < 4; ++m_) {                                          \
        int rA = aRowBase + m_ * 16 + r15;                                    \
        const uint8_t* rp = lds + (bo) + ((MH) * 1024 + rA * 8) * 16;         \
        i32x4 lo = *(const i32x4*)(rp + perm0);                               \
        i32x4 hi = *(const i32x4*)(rp + perm1);                               \
        _Pragma("unroll")                                                     \
        for (int q_ = 0; q_ < 4; ++q_) { af[m_][q_] = lo[q_]; af[m_][4 + q_] = hi[q_]; } \
    }

#define MFMA_BLOCK(MH)                                                        \
    __builtin_amdgcn_s_setprio(1);                                            \
    _Pragma("unroll")                                                         \
    for (int m_ = 0; m_ < 4; ++m_)                                            \
        _Pragma("unroll")                                                     \
        for (int n_ = 0; n_ < 4; ++n_)                                        \
            acc[(MH) * 4 + m_][n_] =                                          \
                __builtin_amdgcn_mfma_scale_f32_16x16x128_f8f6f4(             \
                    af[m_], bf[n_], acc[(MH) * 4 + m_][n_],                   \
                    0, 0, 0, 127, 0, 127);                                    \
    __builtin_amdgcn_s_setprio(0);

    for (int t = 0; t < NKT; ++t) {
        const unsigned bo = (unsigned)(t & 1) << 16;
        uint8_t* nbuf = &lds[(unsigned)((t + 1) & 1) << 16];  // tile t+1 buf
        uint8_t* cbuf = &lds[bo];                             // tile t+2 buf
        // ---- p0: complete tile t+1's staging; compute mh0 ----
        if (t + 1 < NKT) { STAGE_B(1, t + 1, nbuf); STAGE_A(1, t + 1, nbuf); }
        LOAD_BF(bo);
        LOAD_AF(bo, 0);
        MFMA_BLOCK(0);
        barrier_fenced();   // p0 reads of bo (A0,B0,B1 regions) done everywhere
        // ---- p1: start tile t+2's staging (into bo's consumed regions) ----
        if (t + 2 < NKT) { STAGE_A(0, t + 2, cbuf); STAGE_B(0, t + 2, cbuf); }
        LOAD_AF(bo, 1);
        MFMA_BLOCK(1);
        if (t + 2 < NKT)      asm volatile("s_waitcnt vmcnt(4)" ::: "memory");
        else if (t + 1 < NKT) asm volatile("s_waitcnt vmcnt(0)" ::: "memory");
        barrier_fenced();
    }

    // ---- epilogue: fp16 double-rounding emulation, store f32 ----
    float s = s_in[0] * s_w[0];
    int g4 = g * 4;
#pragma unroll
    for (int n = 0; n < 4; ++n) {
        int col = col0 + wc * 64 + n * 16 + r15;
        __half hb = __float2half(bias[col]);
#pragma unroll
        for (int mh = 0; mh < 2; ++mh)
#pragma unroll
            for (int m = 0; m < 4; ++m) {
                int rbase = row0 + wr * 128 + mh * 64 + m * 16 + g4;
#pragma unroll
                for (int r = 0; r < 4; ++r) {
                    __half h = __float2half(acc[mh * 4 + m][n][r] * s);
                    out[(size_t)(rbase + r) * NDIM + col] =
                        __half2float(__hadd(h, hb));
                }
            }
    }
#undef STAGE_A
#undef STAGE_B
#undef LOAD_BF
#undef LOAD_AF
#undef MFMA_BLOCK
}

// ---------------------------------------------------------------------------
extern "C" void kernel_launch(void* const* d_in, const int* in_sizes, int n_in,
                              void* d_out, int out_size, void* d_ws, size_t ws_size,
                              hipStream_t stream) {
    const float* x      = (const float*)d_in[0];   // [16384, 2048]
    const float* weight = (const float*)d_in[1];   // [2048, 2048]
    const float* bias   = (const float*)d_in[2];   // [2048]
    const float* s_in   = (const float*)d_in[3];   // [1]
    const float* s_w    = (const float*)d_in[4];   // [1]
    float* out          = (float*)d_out;

    uint8_t* xq = (uint8_t*)d_ws;                          // 33.5 MB
    uint8_t* wq = (uint8_t*)d_ws + (size_t)MDIM * KDIM;    // 4.2 MB

    quant_both_kernel<<<2304, 256, 0, stream>>>(x, xq, weight, wq, s_in, s_w);

    dim3 grid((MDIM / BM) * (NDIM / BN));   // 64 * 8 = 512
    gemm_fp8_kernel<<<grid, 512, 131072, stream>>>(xq, wq, bias, s_in, s_w, out);
}